// Round 5
// baseline (553.801 us; speedup 1.0000x reference)
//
#include <hip/hip_runtime.h>
#include <cstdint>
#include <cstddef>

#define DI __device__ __forceinline__

typedef __bf16 bf16x8 __attribute__((ext_vector_type(8)));
typedef float f32x4 __attribute__((ext_vector_type(4)));

constexpr int Bb = 4, Ss = 4096, Cc = 256, Ee = 256;

// ---- ws layout (bytes). nz=2 footprint == proven 49 MiB layout ----
constexpr size_t OFF_QHI = 786432;   // 8 MiB  [B*S][C] u16
constexpr size_t OFF_QLO = 9175040;  // 8 MiB
constexpr size_t OFF_KHI = 17563648; // 8 MiB  [B][128 kt][16KB image]
constexpr size_t OFF_KLO = 25952256; // 8 MiB
constexpr size_t OFF_VHI = 34340864; // 8 MiB  [B][128 kt][16KB image]
constexpr size_t OFF_PML = 42729472; // nz*128KiB [z][b][qt][2][64] f32
// P1 partials (bf16, 8 MiB each) start at OFF_PML + nz*131072.

DI unsigned bf_hi(float f) {
  unsigned u = __builtin_bit_cast(unsigned, f);
  return (u + 0x7fffu + ((u >> 16) & 1u)) >> 16;
}
DI float bf_f(unsigned h) { return __builtin_bit_cast(float, h << 16); }

DI unsigned cvtpk(float a, float b) {
  unsigned r;
  asm("v_cvt_pk_bf16_f32 %0, %1, %2" : "=v"(r) : "v"(a), "v"(b));
  return r;
}
// split float4 into bf16-hi pair-words and bf16-lo pair-words
DI void split4(float4 v, uint2& h, uint2& l) {
  unsigned h01 = cvtpk(v.x, v.y), h23 = cvtpk(v.z, v.w);
  float e0 = __builtin_bit_cast(float, h01 << 16);
  float e1 = __builtin_bit_cast(float, h01 & 0xffff0000u);
  float e2 = __builtin_bit_cast(float, h23 << 16);
  float e3 = __builtin_bit_cast(float, h23 & 0xffff0000u);
  h = make_uint2(h01, h23);
  l = make_uint2(cvtpk(v.x - e0, v.y - e1), cvtpk(v.z - e2, v.w - e3));
}

DI f32x4 mfma16(bf16x8 a, bf16x8 b, f32x4 c) {
  return __builtin_amdgcn_mfma_f32_16x16x32_bf16(a, b, c, 0, 0, 0);
}

DI void gl16(const void* g, void* l) {
  __builtin_amdgcn_global_load_lds(
      (const __attribute__((address_space(1))) unsigned*)g,
      (__attribute__((address_space(3))) unsigned*)l, 16, 0, 0);
}

// K image: [32 rows][512B], byte = row*512 + ((col*2) ^ ((row&7)<<4))
// V image: [256 e][64B] packed 2 rows per 128B:
//   byte = (e>>1)*128 + (((e&1)*64 + k*2) ^ (((e>>1)&7)<<4))

// ---------------- W transpose ----------------
__global__ __launch_bounds__(256) void k_transpose(
    const float* __restrict__ wq, const float* __restrict__ wk,
    const float* __restrict__ wv, float* __restrict__ wt) {
  const float* src = blockIdx.x == 0 ? wq : (blockIdx.x == 1 ? wk : wv);
  float* dst = wt + (size_t)blockIdx.x * Cc * Cc;
  const int n = threadIdx.x;
  for (int k = 0; k < Cc; k++) dst[n * Cc + k] = src[k * Cc + n];
}

// ---------------- fused QKV projection ----------------
__global__ __launch_bounds__(256, 2) void k_proj(
    const float* __restrict__ x, const float* __restrict__ wt,
    const float* __restrict__ bq, const float* __restrict__ bk,
    const float* __restrict__ bv, char* __restrict__ ws) {
  __shared__ __align__(16) unsigned short xh[64 * 64], xl[64 * 64];
  __shared__ __align__(16) unsigned short wh[64 * 64], wl[64 * 64];
  const int t = threadIdx.x, lane = t & 63, wid = t >> 6;
  const int mat = blockIdx.z;
  const int n0 = blockIdx.y * 64, m0 = blockIdx.x * 64;
  const float* wm = wt + (size_t)mat * Cc * Cc;
  const float* bias = mat == 0 ? bq : (mat == 1 ? bk : bv);

  f32x4 acc[4];
#pragma unroll
  for (int f = 0; f < 4; f++) acc[f] = (f32x4){0.f, 0.f, 0.f, 0.f};

  const int srow = t >> 2, scol = (t & 3) * 16;

  for (int k0 = 0; k0 < Cc; k0 += 64) {
    const float* xs = x + (size_t)(m0 + srow) * Cc + k0 + scol;
    const float* wsrc = wm + (size_t)(n0 + srow) * Cc + k0 + scol;
#pragma unroll
    for (int j = 0; j < 16; j += 4) {
      const int off = srow * 128 + (((scol + j) * 2) ^ ((srow & 7) << 4));
      uint2 h, l;
      split4(*(const float4*)(xs + j), h, l);
      *(uint2*)((char*)xh + off) = h;
      *(uint2*)((char*)xl + off) = l;
      split4(*(const float4*)(wsrc + j), h, l);
      *(uint2*)((char*)wh + off) = h;
      *(uint2*)((char*)wl + off) = l;
    }
    __syncthreads();
#pragma unroll
    for (int c2 = 0; c2 < 2; c2++) {
      const int arow = wid * 16 + (lane & 15);
      const int aby = arow * 128 + ((c2 * 64 + (lane >> 4) * 16) ^ ((arow & 7) << 4));
      bf16x8 ah = *(const bf16x8*)((const char*)xh + aby);
      bf16x8 al = *(const bf16x8*)((const char*)xl + aby);
#pragma unroll
      for (int f = 0; f < 4; f++) {
        const int brow = f * 16 + (lane & 15);
        const int bby = brow * 128 + ((c2 * 64 + (lane >> 4) * 16) ^ ((brow & 7) << 4));
        bf16x8 bh = *(const bf16x8*)((const char*)wh + bby);
        bf16x8 bl = *(const bf16x8*)((const char*)wl + bby);
        acc[f] = mfma16(ah, bh, acc[f]);
        acc[f] = mfma16(al, bh, acc[f]);
        acc[f] = mfma16(ah, bl, acc[f]);
      }
    }
    __syncthreads();
  }

  const int mgbase = m0 + wid * 16 + (lane >> 4) * 4;
#pragma unroll
  for (int f = 0; f < 4; f++) {
    const int ncol = n0 + f * 16 + (lane & 15);
    const float bb = bias[ncol];
    if (mat == 0) {  // Q linear hi/lo
      unsigned short* qh = (unsigned short*)(ws + OFF_QHI);
      unsigned short* ql = (unsigned short*)(ws + OFF_QLO);
#pragma unroll
      for (int r = 0; r < 4; r++) {
        const int mg = mgbase + r;
        float v = acc[f][r] + bb;
        unsigned h = bf_hi(v);
        qh[(size_t)mg * Cc + ncol] = (unsigned short)h;
        ql[(size_t)mg * Cc + ncol] = (unsigned short)bf_hi(v - bf_f(h));
      }
    } else if (mat == 1) {  // K swizzled images hi/lo
      char* kh = ws + OFF_KHI;
      char* kl = ws + OFF_KLO;
#pragma unroll
      for (int r = 0; r < 4; r++) {
        const int mg = mgbase + r;
        const int bidx = mg >> 12, sg = mg & 4095;
        const int kt = sg >> 5, krow = sg & 31;
        const size_t base = ((size_t)(bidx * 128 + kt)) * 16384 +
                            (size_t)(krow * 512 + ((ncol * 2) ^ ((krow & 7) << 4)));
        float v = acc[f][r] + bb;
        unsigned h = bf_hi(v);
        *(unsigned short*)(kh + base) = (unsigned short)h;
        *(unsigned short*)(kl + base) = (unsigned short)bf_hi(v - bf_f(h));
      }
    } else {  // V swizzled image, hi only
      char* vh = ws + OFF_VHI;
      unsigned h[4];
#pragma unroll
      for (int r = 0; r < 4; r++) h[r] = bf_hi(acc[f][r] + bb);
      const int mg = mgbase;
      const int bidx = mg >> 12, sg = mg & 4095;
      const int kt = sg >> 5, kin = sg & 31;
      const int e = ncol;
      const size_t img = (size_t)((e >> 1) * 128 +
                         (((e & 1) * 64 + kin * 2) ^ (((e >> 1) & 7) << 4)));
      *(uint2*)(vh + ((size_t)(bidx * 128 + kt)) * 16384 + img) =
          make_uint2(h[0] | (h[1] << 16), h[2] | (h[3] << 16));
    }
  }
}

// ---------------- flash attention (kv-split partials) ----------------
// grid (64 qt, B, nz), block 256 (4 waves; wave w owns q-rows w*16..+15,
// full e=256). KBLK=32, single-buffered K/V via global_load_lds.
__global__ __launch_bounds__(256, 3) void k_attn(
    char* __restrict__ ws, float* __restrict__ out, int nz) {
  __shared__ __align__(16) char sbuf[53248];  // 0:Kh 16K:Kl 32K:Vh 48K:P(4x1K)
  const int t = threadIdx.x, lane = t & 63, w = t >> 6;
  const int qt = blockIdx.x, b = blockIdx.y, z = blockIdx.z;
  const int q0 = qt * 64;
  // kt range for this z
  const int ktq = 128 / nz, ktr = 128 % nz;
  const int kt0 = z * ktq + (z < ktr ? z : ktr);
  const int cnt = ktq + (z < ktr ? 1 : 0);

  // ---- Q fragments (hi/lo) ----
  bf16x8 qh_[8], ql_[8];
  {
    const int qrow = q0 + w * 16 + (lane & 15);
    const unsigned short* qph =
        (const unsigned short*)(ws + OFF_QHI) + (size_t)(b * Ss + qrow) * Cc;
    const unsigned short* qpl =
        (const unsigned short*)(ws + OFF_QLO) + (size_t)(b * Ss + qrow) * Cc;
#pragma unroll
    for (int c = 0; c < 8; c++) {
      const int kb = c * 32 + (lane >> 4) * 8;
      qh_[c] = *(const bf16x8*)(qph + kb);
      ql_[c] = *(const bf16x8*)(qpl + kb);
    }
  }

  // ---- staging source offsets (linear: global layout == LDS image) ----
  unsigned srcoff[12];
#pragma unroll
  for (int j = 0; j < 12; j++) {
    const int L = w * 12288 + j * 1024;
    const int r = L >> 14, off = L & 16383;
    const unsigned rb = (r == 0 ? (unsigned)OFF_KHI
                                : (r == 1 ? (unsigned)OFF_KLO : (unsigned)OFF_VHI));
    srcoff[j] = rb + (unsigned)b * 2097152u + (unsigned)kt0 * 16384u +
                (unsigned)off + (unsigned)(lane * 16);
  }

  f32x4 acc[16];
#pragma unroll
  for (int eg = 0; eg < 16; eg++) acc[eg] = (f32x4){0.f, 0.f, 0.f, 0.f};
  float mrun[4] = {-1e30f, -1e30f, -1e30f, -1e30f};
  float lrun[4] = {0.f, 0.f, 0.f, 0.f};

  // ---- prologue: stage tile 0 ----
#pragma unroll
  for (int j = 0; j < 12; j++) gl16(ws + srcoff[j], sbuf + w * 12288 + j * 1024);
  __syncthreads();

  char* const phb = sbuf + 49152 + w * 1024;

  for (int it = 0; it < cnt; it++) {
    // ---- S = Q K^T (3-term split) ----
    f32x4 sacc[2];
    sacc[0] = (f32x4){0.f, 0.f, 0.f, 0.f};
    sacc[1] = (f32x4){0.f, 0.f, 0.f, 0.f};
    __builtin_amdgcn_s_setprio(1);
#pragma unroll
    for (int c = 0; c < 8; c++) {
#pragma unroll
      for (int f = 0; f < 2; f++) {
        const int krow = f * 16 + (lane & 15);
        const int kby = krow * 512 + ((c * 64 + (lane >> 4) * 16) ^ ((krow & 7) << 4));
        bf16x8 bh = *(const bf16x8*)(sbuf + kby);
        bf16x8 bl = *(const bf16x8*)(sbuf + 16384 + kby);
        sacc[f] = mfma16(qh_[c], bh, sacc[f]);
        sacc[f] = mfma16(ql_[c], bh, sacc[f]);
        sacc[f] = mfma16(qh_[c], bl, sacc[f]);
      }
    }
    __builtin_amdgcn_s_setprio(0);

    // ---- online softmax with defer-max (rows q = (lane>>4)*4+r) ----
    float tm[4];
#pragma unroll
    for (int r = 0; r < 4; r++) tm[r] = fmaxf(sacc[0][r], sacc[1][r]);
#pragma unroll
    for (int r = 0; r < 4; r++) {
      tm[r] = fmaxf(tm[r], __shfl_xor(tm[r], 1, 64));
      tm[r] = fmaxf(tm[r], __shfl_xor(tm[r], 2, 64));
      tm[r] = fmaxf(tm[r], __shfl_xor(tm[r], 4, 64));
      tm[r] = fmaxf(tm[r], __shfl_xor(tm[r], 8, 64));
    }
    int ok = 1;
#pragma unroll
    for (int r = 0; r < 4; r++) ok &= (tm[r] <= mrun[r] + 5.5f) ? 1 : 0;
    if (!__all(ok)) {
      float sc[4];
#pragma unroll
      for (int r = 0; r < 4; r++) {
        float mn = fmaxf(mrun[r], tm[r]);
        sc[r] = __expf(mrun[r] - mn);
        mrun[r] = mn;
        lrun[r] *= sc[r];
      }
#pragma unroll
      for (int eg = 0; eg < 16; eg++) {
        acc[eg][0] *= sc[0]; acc[eg][1] *= sc[1];
        acc[eg][2] *= sc[2]; acc[eg][3] *= sc[3];
      }
    }
    float rsum[4] = {0.f, 0.f, 0.f, 0.f};
#pragma unroll
    for (int f = 0; f < 2; f++) {
#pragma unroll
      for (int r = 0; r < 4; r++) {
        float p = __expf(sacc[f][r] - mrun[r]);
        sacc[f][r] = p;
        rsum[r] += p;
      }
    }
#pragma unroll
    for (int r = 0; r < 4; r++) {
      rsum[r] += __shfl_xor(rsum[r], 1, 64);
      rsum[r] += __shfl_xor(rsum[r], 2, 64);
      rsum[r] += __shfl_xor(rsum[r], 4, 64);
      rsum[r] += __shfl_xor(rsum[r], 8, 64);
      lrun[r] += rsum[r];
    }

    // ---- P -> per-wave LDS (single bf16, packed-row swizzle) ----
#pragma unroll
    for (int r = 0; r < 4; r++) {
      const unsigned wpk = cvtpk(sacc[0][r], sacc[1][r]);
      const int q = (lane >> 4) * 4 + r;
      const int c0 = (lane & 15) * 2;
      const int lineb = (q >> 1) * 128, sw = ((q >> 1) & 7) << 4, half = (q & 1) * 64;
      *(unsigned short*)(phb + lineb + ((half + c0) ^ sw)) = (unsigned short)wpk;
      *(unsigned short*)(phb + lineb + ((half + 32 + c0) ^ sw)) =
          (unsigned short)(wpk >> 16);
    }

    // ---- O += P V (single term) ----
    {
      const int q = lane & 15;
      const int pby = (q >> 1) * 128 +
                      (((q & 1) * 64 + (lane >> 4) * 16) ^ (((q >> 1) & 7) << 4));
      bf16x8 pa = *(const bf16x8*)(phb + pby);
      __builtin_amdgcn_s_setprio(1);
#pragma unroll
      for (int eg = 0; eg < 16; eg++) {
        const int erow = eg * 16 + (lane & 15);
        const int vby = (erow >> 1) * 128 +
                        (((erow & 1) * 64 + (lane >> 4) * 16) ^ (((erow >> 1) & 7) << 4));
        bf16x8 bvh = *(const bf16x8*)(sbuf + 32768 + vby);
        acc[eg] = mfma16(pa, bvh, acc[eg]);
      }
      __builtin_amdgcn_s_setprio(0);
    }

    __syncthreads();  // all reads of this tile done
    if (it + 1 < cnt) {
#pragma unroll
      for (int j = 0; j < 12; j++) {
        srcoff[j] += 16384;
        gl16(ws + srcoff[j], sbuf + w * 12288 + j * 1024);
      }
    }
    __syncthreads();  // vmcnt(0) drain: next tile resident
  }

  // ---- epilogue: write partial (z0: f32 into out; z>=1: bf16) + m,l ----
  const int qloc0 = w * 16 + (lane >> 4) * 4;
  if (z == 0) {
#pragma unroll
    for (int eg = 0; eg < 16; eg++) {
      const int e = eg * 16 + (lane & 15);
#pragma unroll
      for (int r = 0; r < 4; r++)
        out[((size_t)(b * Ss + q0 + qloc0 + r)) * Ee + e] = acc[eg][r];
    }
  } else {
    unsigned short* p1 = (unsigned short*)(ws + OFF_PML + (size_t)nz * 131072 +
                                           (size_t)(z - 1) * 8388608);
#pragma unroll
    for (int eg = 0; eg < 16; eg++) {
      const int e = eg * 16 + (lane & 15);
#pragma unroll
      for (int r = 0; r < 4; r++)
        p1[((size_t)((b * 64 + qt) * 64 + qloc0 + r)) * 256 + e] =
            (unsigned short)bf_hi(acc[eg][r]);
    }
  }
  if ((lane & 15) == 0) {
    float* pml = (float*)(ws + OFF_PML);
#pragma unroll
    for (int r = 0; r < 4; r++) {
      const int q = qloc0 + r;
      pml[(((size_t)(z * 4 + b) * 64 + qt) * 2 + 0) * 64 + q] = mrun[r];
      pml[(((size_t)(z * 4 + b) * 64 + qt) * 2 + 1) * 64 + q] = lrun[r];
    }
  }
}

// ---------------- combine partials + sigmoid ----------------
__global__ __launch_bounds__(256) void k_comb(
    char* __restrict__ ws, float* __restrict__ out, int nz) {
  __shared__ float sm[3][64], sl[3][64];
  const int t = threadIdx.x, qt = blockIdx.x, b = blockIdx.y;
  const float* pml = (const float*)(ws + OFF_PML);
  if (t < 64) {
    for (int z = 0; z < nz; z++) {
      sm[z][t] = pml[(((size_t)(z * 4 + b) * 64 + qt) * 2 + 0) * 64 + t];
      sl[z][t] = pml[(((size_t)(z * 4 + b) * 64 + qt) * 2 + 1) * 64 + t];
    }
  }
  __syncthreads();
  const unsigned short* p1 =
      (const unsigned short*)(ws + OFF_PML + (size_t)nz * 131072);
  for (int q = 0; q < 64; q++) {
    const size_t o = ((size_t)(b * Ss + qt * 64 + q)) * Ee + t;
    float M = sm[0][q];
    for (int z = 1; z < nz; z++) M = fmaxf(M, sm[z][q]);
    float a0 = __expf(sm[0][q] - M);
    float num = out[o] * a0, den = sl[0][q] * a0;
    for (int z = 1; z < nz; z++) {
      float az = __expf(sm[z][q] - M);
      float oz = bf_f(p1[(size_t)(z - 1) * 4194304 +
                         ((size_t)((b * 64 + qt) * 64 + q)) * 256 + t]);
      num += oz * az;
      den += sl[z][q] * az;
    }
    float v = num / den;
    out[o] = 1.f / (1.f + __expf(-v));
  }
}

extern "C" void kernel_launch(void* const* d_in, const int* in_sizes, int n_in,
                              void* d_out, int out_size, void* d_ws, size_t ws_size,
                              hipStream_t stream) {
  (void)in_sizes; (void)n_in; (void)out_size;
  const float* x  = (const float*)d_in[0];
  const float* Wq = (const float*)d_in[1];
  const float* bq = (const float*)d_in[2];
  const float* Wk = (const float*)d_in[3];
  const float* bk = (const float*)d_in[4];
  const float* Wv = (const float*)d_in[5];
  const float* bv = (const float*)d_in[6];
  float* out = (float*)d_out;
  char* ws = (char*)d_ws;
  float* wt = (float*)ws;  // 768 KB: [3][256][256] W^T

  // nz=3 needs 59,899,904 B of ws; nz=2 needs the proven 51,380,224 B.
  const int nz = (ws_size >= 60000000u) ? 3 : 2;

  hipLaunchKernelGGL(k_transpose, dim3(3), dim3(256), 0, stream, Wq, Wk, Wv, wt);
  hipLaunchKernelGGL(k_proj, dim3(256, 4, 3), dim3(256), 0, stream,
                     x, wt, bq, bk, bv, ws);
  hipLaunchKernelGGL(k_attn, dim3(64, Bb, nz), dim3(256), 0, stream, ws, out, nz);
  hipLaunchKernelGGL(k_comb, dim3(64, Bb), dim3(256), 0, stream, ws, out, nz);
}

// Round 6
// 383.313 us; speedup vs baseline: 1.4448x; 1.4448x over previous
//
#include <hip/hip_runtime.h>
#include <cstdint>
#include <cstddef>

#define DI __device__ __forceinline__

typedef __bf16 bf16x8 __attribute__((ext_vector_type(8)));
typedef float f32x4 __attribute__((ext_vector_type(4)));

constexpr int Bb = 4, Ss = 4096, Cc = 256, Ee = 256;

// ---- ws layout (bytes). nz=2 footprint == proven 49 MiB layout ----
constexpr size_t OFF_QHI = 786432;   // 8 MiB  [B*S][C] u16
constexpr size_t OFF_QLO = 9175040;  // 8 MiB
constexpr size_t OFF_KHI = 17563648; // 8 MiB  [B][128 kt][16KB image]
constexpr size_t OFF_KLO = 25952256; // 8 MiB
constexpr size_t OFF_VHI = 34340864; // 8 MiB  [B][128 kt][16KB image]
constexpr size_t OFF_PML = 42729472; // nz*128KiB [z][b][qt][2][64] f32
// P1 partials (bf16, 8 MiB each) start at OFF_PML + nz*131072.

DI unsigned bf_hi(float f) {
  unsigned u = __builtin_bit_cast(unsigned, f);
  return (u + 0x7fffu + ((u >> 16) & 1u)) >> 16;
}
DI float bf_f(unsigned h) { return __builtin_bit_cast(float, h << 16); }

DI unsigned cvtpk(float a, float b) {
  unsigned r;
  asm("v_cvt_pk_bf16_f32 %0, %1, %2" : "=v"(r) : "v"(a), "v"(b));
  return r;
}
// split float4 into bf16-hi pair-words and bf16-lo pair-words
DI void split4(float4 v, uint2& h, uint2& l) {
  unsigned h01 = cvtpk(v.x, v.y), h23 = cvtpk(v.z, v.w);
  float e0 = __builtin_bit_cast(float, h01 << 16);
  float e1 = __builtin_bit_cast(float, h01 & 0xffff0000u);
  float e2 = __builtin_bit_cast(float, h23 << 16);
  float e3 = __builtin_bit_cast(float, h23 & 0xffff0000u);
  h = make_uint2(h01, h23);
  l = make_uint2(cvtpk(v.x - e0, v.y - e1), cvtpk(v.z - e2, v.w - e3));
}

DI f32x4 mfma16(bf16x8 a, bf16x8 b, f32x4 c) {
  return __builtin_amdgcn_mfma_f32_16x16x32_bf16(a, b, c, 0, 0, 0);
}

DI void gl16(const void* g, void* l) {
  __builtin_amdgcn_global_load_lds(
      (const __attribute__((address_space(1))) unsigned*)g,
      (__attribute__((address_space(3))) unsigned*)l, 16, 0, 0);
}

// K image: [32 rows][512B], byte = row*512 + ((col*2) ^ ((row&7)<<4))
// V image: [256 e][64B] packed 2 rows per 128B:
//   byte = (e>>1)*128 + (((e&1)*64 + k*2) ^ (((e>>1)&7)<<4))

// ---------------- W transpose ----------------
__global__ __launch_bounds__(256) void k_transpose(
    const float* __restrict__ wq, const float* __restrict__ wk,
    const float* __restrict__ wv, float* __restrict__ wt) {
  const float* src = blockIdx.x == 0 ? wq : (blockIdx.x == 1 ? wk : wv);
  float* dst = wt + (size_t)blockIdx.x * Cc * Cc;
  const int n = threadIdx.x;
  for (int k = 0; k < Cc; k++) dst[n * Cc + k] = src[k * Cc + n];
}

// ---------------- fused QKV projection ----------------
__global__ __launch_bounds__(256, 2) void k_proj(
    const float* __restrict__ x, const float* __restrict__ wt,
    const float* __restrict__ bq, const float* __restrict__ bk,
    const float* __restrict__ bv, char* __restrict__ ws) {
  __shared__ __align__(16) unsigned short xh[64 * 64], xl[64 * 64];
  __shared__ __align__(16) unsigned short wh[64 * 64], wl[64 * 64];
  const int t = threadIdx.x, lane = t & 63, wid = t >> 6;
  const int mat = blockIdx.z;
  const int n0 = blockIdx.y * 64, m0 = blockIdx.x * 64;
  const float* wm = wt + (size_t)mat * Cc * Cc;
  const float* bias = mat == 0 ? bq : (mat == 1 ? bk : bv);

  f32x4 acc[4];
#pragma unroll
  for (int f = 0; f < 4; f++) acc[f] = (f32x4){0.f, 0.f, 0.f, 0.f};

  const int srow = t >> 2, scol = (t & 3) * 16;

  for (int k0 = 0; k0 < Cc; k0 += 64) {
    const float* xs = x + (size_t)(m0 + srow) * Cc + k0 + scol;
    const float* wsrc = wm + (size_t)(n0 + srow) * Cc + k0 + scol;
#pragma unroll
    for (int j = 0; j < 16; j += 4) {
      const int off = srow * 128 + (((scol + j) * 2) ^ ((srow & 7) << 4));
      uint2 h, l;
      split4(*(const float4*)(xs + j), h, l);
      *(uint2*)((char*)xh + off) = h;
      *(uint2*)((char*)xl + off) = l;
      split4(*(const float4*)(wsrc + j), h, l);
      *(uint2*)((char*)wh + off) = h;
      *(uint2*)((char*)wl + off) = l;
    }
    __syncthreads();
#pragma unroll
    for (int c2 = 0; c2 < 2; c2++) {
      const int arow = wid * 16 + (lane & 15);
      const int aby = arow * 128 + ((c2 * 64 + (lane >> 4) * 16) ^ ((arow & 7) << 4));
      bf16x8 ah = *(const bf16x8*)((const char*)xh + aby);
      bf16x8 al = *(const bf16x8*)((const char*)xl + aby);
#pragma unroll
      for (int f = 0; f < 4; f++) {
        const int brow = f * 16 + (lane & 15);
        const int bby = brow * 128 + ((c2 * 64 + (lane >> 4) * 16) ^ ((brow & 7) << 4));
        bf16x8 bh = *(const bf16x8*)((const char*)wh + bby);
        bf16x8 bl = *(const bf16x8*)((const char*)wl + bby);
        acc[f] = mfma16(ah, bh, acc[f]);
        acc[f] = mfma16(al, bh, acc[f]);
        acc[f] = mfma16(ah, bl, acc[f]);
      }
    }
    __syncthreads();
  }

  const int mgbase = m0 + wid * 16 + (lane >> 4) * 4;
#pragma unroll
  for (int f = 0; f < 4; f++) {
    const int ncol = n0 + f * 16 + (lane & 15);
    const float bb = bias[ncol];
    if (mat == 0) {  // Q linear hi/lo
      unsigned short* qh = (unsigned short*)(ws + OFF_QHI);
      unsigned short* ql = (unsigned short*)(ws + OFF_QLO);
#pragma unroll
      for (int r = 0; r < 4; r++) {
        const int mg = mgbase + r;
        float v = acc[f][r] + bb;
        unsigned h = bf_hi(v);
        qh[(size_t)mg * Cc + ncol] = (unsigned short)h;
        ql[(size_t)mg * Cc + ncol] = (unsigned short)bf_hi(v - bf_f(h));
      }
    } else if (mat == 1) {  // K swizzled images hi/lo
      char* kh = ws + OFF_KHI;
      char* kl = ws + OFF_KLO;
#pragma unroll
      for (int r = 0; r < 4; r++) {
        const int mg = mgbase + r;
        const int bidx = mg >> 12, sg = mg & 4095;
        const int kt = sg >> 5, krow = sg & 31;
        const size_t base = ((size_t)(bidx * 128 + kt)) * 16384 +
                            (size_t)(krow * 512 + ((ncol * 2) ^ ((krow & 7) << 4)));
        float v = acc[f][r] + bb;
        unsigned h = bf_hi(v);
        *(unsigned short*)(kh + base) = (unsigned short)h;
        *(unsigned short*)(kl + base) = (unsigned short)bf_hi(v - bf_f(h));
      }
    } else {  // V swizzled image, hi only
      char* vh = ws + OFF_VHI;
      unsigned h[4];
#pragma unroll
      for (int r = 0; r < 4; r++) h[r] = bf_hi(acc[f][r] + bb);
      const int mg = mgbase;
      const int bidx = mg >> 12, sg = mg & 4095;
      const int kt = sg >> 5, kin = sg & 31;
      const int e = ncol;
      const size_t img = (size_t)((e >> 1) * 128 +
                         (((e & 1) * 64 + kin * 2) ^ (((e >> 1) & 7) << 4)));
      *(uint2*)(vh + ((size_t)(bidx * 128 + kt)) * 16384 + img) =
          make_uint2(h[0] | (h[1] << 16), h[2] | (h[3] << 16));
    }
  }
}

// ---------------- flash attention (kv-split partials) ----------------
// grid (64 qt, B, nz), block 256 (4 waves; wave w owns q-rows w*16..+15,
// full e=256). KBLK=32, single-buffered K/V via global_load_lds.
// NOTE: __launch_bounds__ min-waves stays at 2 — r5's (256,3) capped VGPR
// to 84 and spilled acc[16] to scratch (WRITE_SIZE 24->373MB, +58% time).
// 3 blocks/CU residency comes from resources (52KB LDS, VGPR<=170), not
// from the bound.
__global__ __launch_bounds__(256, 2) void k_attn(
    char* __restrict__ ws, float* __restrict__ out, int nz) {
  __shared__ __align__(16) char sbuf[53248];  // 0:Kh 16K:Kl 32K:Vh 48K:P(4x1K)
  const int t = threadIdx.x, lane = t & 63, w = t >> 6;
  const int qt = blockIdx.x, b = blockIdx.y, z = blockIdx.z;
  const int q0 = qt * 64;
  // kt range for this z
  const int ktq = 128 / nz, ktr = 128 % nz;
  const int kt0 = z * ktq + (z < ktr ? z : ktr);
  const int cnt = ktq + (z < ktr ? 1 : 0);

  // ---- Q fragments (hi/lo) ----
  bf16x8 qh_[8], ql_[8];
  {
    const int qrow = q0 + w * 16 + (lane & 15);
    const unsigned short* qph =
        (const unsigned short*)(ws + OFF_QHI) + (size_t)(b * Ss + qrow) * Cc;
    const unsigned short* qpl =
        (const unsigned short*)(ws + OFF_QLO) + (size_t)(b * Ss + qrow) * Cc;
#pragma unroll
    for (int c = 0; c < 8; c++) {
      const int kb = c * 32 + (lane >> 4) * 8;
      qh_[c] = *(const bf16x8*)(qph + kb);
      ql_[c] = *(const bf16x8*)(qpl + kb);
    }
  }

  // ---- staging source offsets (linear: global layout == LDS image) ----
  unsigned srcoff[12];
#pragma unroll
  for (int j = 0; j < 12; j++) {
    const int L = w * 12288 + j * 1024;
    const int r = L >> 14, off = L & 16383;
    const unsigned rb = (r == 0 ? (unsigned)OFF_KHI
                                : (r == 1 ? (unsigned)OFF_KLO : (unsigned)OFF_VHI));
    srcoff[j] = rb + (unsigned)b * 2097152u + (unsigned)kt0 * 16384u +
                (unsigned)off + (unsigned)(lane * 16);
  }

  f32x4 acc[16];
#pragma unroll
  for (int eg = 0; eg < 16; eg++) acc[eg] = (f32x4){0.f, 0.f, 0.f, 0.f};
  float mrun[4] = {-1e30f, -1e30f, -1e30f, -1e30f};
  float lrun[4] = {0.f, 0.f, 0.f, 0.f};

  // ---- prologue: stage tile 0 ----
#pragma unroll
  for (int j = 0; j < 12; j++) gl16(ws + srcoff[j], sbuf + w * 12288 + j * 1024);
  __syncthreads();

  char* const phb = sbuf + 49152 + w * 1024;

  for (int it = 0; it < cnt; it++) {
    // ---- S = Q K^T (3-term split) ----
    f32x4 sacc[2];
    sacc[0] = (f32x4){0.f, 0.f, 0.f, 0.f};
    sacc[1] = (f32x4){0.f, 0.f, 0.f, 0.f};
    __builtin_amdgcn_s_setprio(1);
#pragma unroll
    for (int c = 0; c < 8; c++) {
#pragma unroll
      for (int f = 0; f < 2; f++) {
        const int krow = f * 16 + (lane & 15);
        const int kby = krow * 512 + ((c * 64 + (lane >> 4) * 16) ^ ((krow & 7) << 4));
        bf16x8 bh = *(const bf16x8*)(sbuf + kby);
        bf16x8 bl = *(const bf16x8*)(sbuf + 16384 + kby);
        sacc[f] = mfma16(qh_[c], bh, sacc[f]);
        sacc[f] = mfma16(ql_[c], bh, sacc[f]);
        sacc[f] = mfma16(qh_[c], bl, sacc[f]);
      }
    }
    __builtin_amdgcn_s_setprio(0);

    // ---- online softmax with defer-max (rows q = (lane>>4)*4+r) ----
    float tm[4];
#pragma unroll
    for (int r = 0; r < 4; r++) tm[r] = fmaxf(sacc[0][r], sacc[1][r]);
#pragma unroll
    for (int r = 0; r < 4; r++) {
      tm[r] = fmaxf(tm[r], __shfl_xor(tm[r], 1, 64));
      tm[r] = fmaxf(tm[r], __shfl_xor(tm[r], 2, 64));
      tm[r] = fmaxf(tm[r], __shfl_xor(tm[r], 4, 64));
      tm[r] = fmaxf(tm[r], __shfl_xor(tm[r], 8, 64));
    }
    int ok = 1;
#pragma unroll
    for (int r = 0; r < 4; r++) ok &= (tm[r] <= mrun[r] + 5.5f) ? 1 : 0;
    if (!__all(ok)) {
      float sc[4];
#pragma unroll
      for (int r = 0; r < 4; r++) {
        float mn = fmaxf(mrun[r], tm[r]);
        sc[r] = __expf(mrun[r] - mn);
        mrun[r] = mn;
        lrun[r] *= sc[r];
      }
#pragma unroll
      for (int eg = 0; eg < 16; eg++) {
        acc[eg][0] *= sc[0]; acc[eg][1] *= sc[1];
        acc[eg][2] *= sc[2]; acc[eg][3] *= sc[3];
      }
    }
    float rsum[4] = {0.f, 0.f, 0.f, 0.f};
#pragma unroll
    for (int f = 0; f < 2; f++) {
#pragma unroll
      for (int r = 0; r < 4; r++) {
        float p = __expf(sacc[f][r] - mrun[r]);
        sacc[f][r] = p;
        rsum[r] += p;
      }
    }
#pragma unroll
    for (int r = 0; r < 4; r++) {
      rsum[r] += __shfl_xor(rsum[r], 1, 64);
      rsum[r] += __shfl_xor(rsum[r], 2, 64);
      rsum[r] += __shfl_xor(rsum[r], 4, 64);
      rsum[r] += __shfl_xor(rsum[r], 8, 64);
      lrun[r] += rsum[r];
    }

    // ---- P -> per-wave LDS (single bf16, packed-row swizzle) ----
#pragma unroll
    for (int r = 0; r < 4; r++) {
      const unsigned wpk = cvtpk(sacc[0][r], sacc[1][r]);
      const int q = (lane >> 4) * 4 + r;
      const int c0 = (lane & 15) * 2;
      const int lineb = (q >> 1) * 128, sw = ((q >> 1) & 7) << 4, half = (q & 1) * 64;
      *(unsigned short*)(phb + lineb + ((half + c0) ^ sw)) = (unsigned short)wpk;
      *(unsigned short*)(phb + lineb + ((half + 32 + c0) ^ sw)) =
          (unsigned short)(wpk >> 16);
    }

    // ---- O += P V (single term) ----
    {
      const int q = lane & 15;
      const int pby = (q >> 1) * 128 +
                      (((q & 1) * 64 + (lane >> 4) * 16) ^ (((q >> 1) & 7) << 4));
      bf16x8 pa = *(const bf16x8*)(phb + pby);
      __builtin_amdgcn_s_setprio(1);
#pragma unroll
      for (int eg = 0; eg < 16; eg++) {
        const int erow = eg * 16 + (lane & 15);
        const int vby = (erow >> 1) * 128 +
                        (((erow & 1) * 64 + (lane >> 4) * 16) ^ (((erow >> 1) & 7) << 4));
        bf16x8 bvh = *(const bf16x8*)(sbuf + 32768 + vby);
        acc[eg] = mfma16(pa, bvh, acc[eg]);
      }
      __builtin_amdgcn_s_setprio(0);
    }

    __syncthreads();  // all reads of this tile done
    if (it + 1 < cnt) {
#pragma unroll
      for (int j = 0; j < 12; j++) {
        srcoff[j] += 16384;
        gl16(ws + srcoff[j], sbuf + w * 12288 + j * 1024);
      }
    }
    __syncthreads();  // vmcnt(0) drain: next tile resident
  }

  // ---- epilogue: write partial (z0: f32 into out; z>=1: bf16) + m,l ----
  const int qloc0 = w * 16 + (lane >> 4) * 4;
  if (z == 0) {
#pragma unroll
    for (int eg = 0; eg < 16; eg++) {
      const int e = eg * 16 + (lane & 15);
#pragma unroll
      for (int r = 0; r < 4; r++)
        out[((size_t)(b * Ss + q0 + qloc0 + r)) * Ee + e] = acc[eg][r];
    }
  } else {
    unsigned short* p1 = (unsigned short*)(ws + OFF_PML + (size_t)nz * 131072 +
                                           (size_t)(z - 1) * 8388608);
#pragma unroll
    for (int eg = 0; eg < 16; eg++) {
      const int e = eg * 16 + (lane & 15);
#pragma unroll
      for (int r = 0; r < 4; r++)
        p1[((size_t)((b * 64 + qt) * 64 + qloc0 + r)) * 256 + e] =
            (unsigned short)bf_hi(acc[eg][r]);
    }
  }
  if ((lane & 15) == 0) {
    float* pml = (float*)(ws + OFF_PML);
#pragma unroll
    for (int r = 0; r < 4; r++) {
      const int q = qloc0 + r;
      pml[(((size_t)(z * 4 + b) * 64 + qt) * 2 + 0) * 64 + q] = mrun[r];
      pml[(((size_t)(z * 4 + b) * 64 + qt) * 2 + 1) * 64 + q] = lrun[r];
    }
  }
}

// ---------------- combine partials + sigmoid ----------------
// grid (64 qt, B, 4 qz), block 256 (thread = e; 16 q-rows per block).
__global__ __launch_bounds__(256) void k_comb(
    char* __restrict__ ws, float* __restrict__ out, int nz) {
  __shared__ float sm[3][16], sl[3][16];
  const int t = threadIdx.x, qt = blockIdx.x, b = blockIdx.y, qz = blockIdx.z;
  const float* pml = (const float*)(ws + OFF_PML);
  if (t < 16 * nz) {
    const int z = t >> 4, qq = t & 15;
    const int q = qz * 16 + qq;
    sm[z][qq] = pml[(((size_t)(z * 4 + b) * 64 + qt) * 2 + 0) * 64 + q];
    sl[z][qq] = pml[(((size_t)(z * 4 + b) * 64 + qt) * 2 + 1) * 64 + q];
  }
  __syncthreads();
  const unsigned short* p1 =
      (const unsigned short*)(ws + OFF_PML + (size_t)nz * 131072);
  for (int qi = 0; qi < 16; qi++) {
    const int q = qz * 16 + qi;
    const size_t o = ((size_t)(b * Ss + qt * 64 + q)) * Ee + t;
    float M = sm[0][qi];
    for (int z = 1; z < nz; z++) M = fmaxf(M, sm[z][qi]);
    float a0 = __expf(sm[0][qi] - M);
    float num = out[o] * a0, den = sl[0][qi] * a0;
    for (int z = 1; z < nz; z++) {
      float az = __expf(sm[z][qi] - M);
      float oz = bf_f(p1[(size_t)(z - 1) * 4194304 +
                         ((size_t)((b * 64 + qt) * 64 + q)) * 256 + t]);
      num += oz * az;
      den += sl[z][qi] * az;
    }
    float v = num / den;
    out[o] = 1.f / (1.f + __expf(-v));
  }
}

extern "C" void kernel_launch(void* const* d_in, const int* in_sizes, int n_in,
                              void* d_out, int out_size, void* d_ws, size_t ws_size,
                              hipStream_t stream) {
  (void)in_sizes; (void)n_in; (void)out_size;
  const float* x  = (const float*)d_in[0];
  const float* Wq = (const float*)d_in[1];
  const float* bq = (const float*)d_in[2];
  const float* Wk = (const float*)d_in[3];
  const float* bk = (const float*)d_in[4];
  const float* Wv = (const float*)d_in[5];
  const float* bv = (const float*)d_in[6];
  float* out = (float*)d_out;
  char* ws = (char*)d_ws;
  float* wt = (float*)ws;  // 768 KB: [3][256][256] W^T

  // nz=3 needs 59,899,904 B of ws; nz=2 needs the proven 51,380,224 B.
  const int nz = (ws_size >= 60000000u) ? 3 : 2;

  hipLaunchKernelGGL(k_transpose, dim3(3), dim3(256), 0, stream, Wq, Wk, Wv, wt);
  hipLaunchKernelGGL(k_proj, dim3(256, 4, 3), dim3(256), 0, stream,
                     x, wt, bq, bk, bv, ws);
  hipLaunchKernelGGL(k_attn, dim3(64, Bb, nz), dim3(256), 0, stream, ws, out, nz);
  hipLaunchKernelGGL(k_comb, dim3(64, Bb, 4), dim3(256), 0, stream, ws, out, nz);
}

// Round 8
// 280.368 us; speedup vs baseline: 1.9753x; 1.3672x over previous
//
#include <hip/hip_runtime.h>
#include <cstdint>
#include <cstddef>

#define DI __device__ __forceinline__

typedef __bf16 bf16x8 __attribute__((ext_vector_type(8)));
typedef _Float16 f16x8 __attribute__((ext_vector_type(8)));
typedef float f32x4 __attribute__((ext_vector_type(4)));

constexpr int Bb = 4, Ss = 4096, Cc = 256, Ee = 256;

// ---- ws layout (bytes); total 43,122,688 (< proven-safe 49 MiB) ----
// NOTE r7 bug: fp16 tensors are 8 MiB EACH (B*S*C*2B); r7 packed them at
// 4 MiB strides -> Q/K/V/PML all overlapped (absmax 0.736). Fixed strides:
constexpr size_t OFF_Q   = 786432;    // 8 MiB [B*S][C] fp16
constexpr size_t OFF_K   = 9175040;   // 8 MiB [B][128 kt][16KB image] fp16
constexpr size_t OFF_V   = 17563648;  // 8 MiB [B][128 kt][16KB image] fp16
constexpr size_t OFF_PML = 25952256;  // 3*128KiB [z][b][qt][2][64] f32
// P1 partials (bf16, 8 MiB each for z=1,2) start at OFF_PML + 3*131072.

DI unsigned bf_hi(float f) {
  unsigned u = __builtin_bit_cast(unsigned, f);
  return (u + 0x7fffu + ((u >> 16) & 1u)) >> 16;
}
DI float bf_f(unsigned h) { return __builtin_bit_cast(float, h << 16); }

DI unsigned cvtpk(float a, float b) {  // bf16 pair pack (k_proj staging)
  unsigned r;
  asm("v_cvt_pk_bf16_f32 %0, %1, %2" : "=v"(r) : "v"(a), "v"(b));
  return r;
}
// split float4 into bf16-hi pair-words and bf16-lo pair-words
DI void split4(float4 v, uint2& h, uint2& l) {
  unsigned h01 = cvtpk(v.x, v.y), h23 = cvtpk(v.z, v.w);
  float e0 = __builtin_bit_cast(float, h01 << 16);
  float e1 = __builtin_bit_cast(float, h01 & 0xffff0000u);
  float e2 = __builtin_bit_cast(float, h23 << 16);
  float e3 = __builtin_bit_cast(float, h23 & 0xffff0000u);
  h = make_uint2(h01, h23);
  l = make_uint2(cvtpk(v.x - e0, v.y - e1), cvtpk(v.z - e2, v.w - e3));
}
DI unsigned short f16b(float v) {
  _Float16 h = (_Float16)v;  // RNE v_cvt_f16_f32
  return __builtin_bit_cast(unsigned short, h);
}
DI unsigned pkf16(float a, float b) {  // v_cvt_pkrtz_f16_f32 (RTZ ok for P)
  return __builtin_bit_cast(unsigned, __builtin_amdgcn_cvt_pkrtz(a, b));
}

DI f32x4 mfma16(bf16x8 a, bf16x8 b, f32x4 c) {
  return __builtin_amdgcn_mfma_f32_16x16x32_bf16(a, b, c, 0, 0, 0);
}
DI f32x4 mfma16f(f16x8 a, f16x8 b, f32x4 c) {
  return __builtin_amdgcn_mfma_f32_16x16x32_f16(a, b, c, 0, 0, 0);
}

DI void gl16(const void* g, void* l) {
  __builtin_amdgcn_global_load_lds(
      (const __attribute__((address_space(1))) unsigned*)g,
      (__attribute__((address_space(3))) unsigned*)l, 16, 0, 0);
}

// K image: [32 rows][512B], byte = row*512 + ((col*2) ^ ((row&7)<<4))
// V image: [256 e][64B] packed 2 rows per 128B:
//   byte = (e>>1)*128 + (((e&1)*64 + k*2) ^ (((e>>1)&7)<<4))

// ---------------- W transpose ----------------
__global__ __launch_bounds__(256) void k_transpose(
    const float* __restrict__ wq, const float* __restrict__ wk,
    const float* __restrict__ wv, float* __restrict__ wt) {
  const float* src = blockIdx.x == 0 ? wq : (blockIdx.x == 1 ? wk : wv);
  float* dst = wt + (size_t)blockIdx.x * Cc * Cc;
  const int n = threadIdx.x;
  for (int k = 0; k < Cc; k++) dst[n * Cc + k] = src[k * Cc + n];
}

// ---------------- fused QKV projection ----------------
// Internal math: 3-term bf16 hi/lo split (rel err ~2^-15); outputs fp16 RNE.
__global__ __launch_bounds__(256, 2) void k_proj(
    const float* __restrict__ x, const float* __restrict__ wt,
    const float* __restrict__ bq, const float* __restrict__ bk,
    const float* __restrict__ bv, char* __restrict__ ws) {
  __shared__ __align__(16) unsigned short xh[64 * 64], xl[64 * 64];
  __shared__ __align__(16) unsigned short wh[64 * 64], wl[64 * 64];
  const int t = threadIdx.x, lane = t & 63, wid = t >> 6;
  const int mat = blockIdx.z;
  const int n0 = blockIdx.y * 64, m0 = blockIdx.x * 64;
  const float* wm = wt + (size_t)mat * Cc * Cc;
  const float* bias = mat == 0 ? bq : (mat == 1 ? bk : bv);

  f32x4 acc[4];
#pragma unroll
  for (int f = 0; f < 4; f++) acc[f] = (f32x4){0.f, 0.f, 0.f, 0.f};

  const int srow = t >> 2, scol = (t & 3) * 16;

  for (int k0 = 0; k0 < Cc; k0 += 64) {
    const float* xs = x + (size_t)(m0 + srow) * Cc + k0 + scol;
    const float* wsrc = wm + (size_t)(n0 + srow) * Cc + k0 + scol;
#pragma unroll
    for (int j = 0; j < 16; j += 4) {
      const int off = srow * 128 + (((scol + j) * 2) ^ ((srow & 7) << 4));
      uint2 h, l;
      split4(*(const float4*)(xs + j), h, l);
      *(uint2*)((char*)xh + off) = h;
      *(uint2*)((char*)xl + off) = l;
      split4(*(const float4*)(wsrc + j), h, l);
      *(uint2*)((char*)wh + off) = h;
      *(uint2*)((char*)wl + off) = l;
    }
    __syncthreads();
#pragma unroll
    for (int c2 = 0; c2 < 2; c2++) {
      const int arow = wid * 16 + (lane & 15);
      const int aby = arow * 128 + ((c2 * 64 + (lane >> 4) * 16) ^ ((arow & 7) << 4));
      bf16x8 ah = *(const bf16x8*)((const char*)xh + aby);
      bf16x8 al = *(const bf16x8*)((const char*)xl + aby);
#pragma unroll
      for (int f = 0; f < 4; f++) {
        const int brow = f * 16 + (lane & 15);
        const int bby = brow * 128 + ((c2 * 64 + (lane >> 4) * 16) ^ ((brow & 7) << 4));
        bf16x8 bh = *(const bf16x8*)((const char*)wh + bby);
        bf16x8 bl = *(const bf16x8*)((const char*)wl + bby);
        acc[f] = mfma16(ah, bh, acc[f]);
        acc[f] = mfma16(al, bh, acc[f]);
        acc[f] = mfma16(ah, bl, acc[f]);
      }
    }
    __syncthreads();
  }

  const int mgbase = m0 + wid * 16 + (lane >> 4) * 4;
#pragma unroll
  for (int f = 0; f < 4; f++) {
    const int ncol = n0 + f * 16 + (lane & 15);
    const float bb = bias[ncol];
    if (mat == 0) {  // Q linear fp16
      unsigned short* qd = (unsigned short*)(ws + OFF_Q);
#pragma unroll
      for (int r = 0; r < 4; r++) {
        const int mg = mgbase + r;
        qd[(size_t)mg * Cc + ncol] = f16b(acc[f][r] + bb);
      }
    } else if (mat == 1) {  // K swizzled image fp16
      char* kf = ws + OFF_K;
#pragma unroll
      for (int r = 0; r < 4; r++) {
        const int mg = mgbase + r;
        const int bidx = mg >> 12, sg = mg & 4095;
        const int kt = sg >> 5, krow = sg & 31;
        const size_t base = ((size_t)(bidx * 128 + kt)) * 16384 +
                            (size_t)(krow * 512 + ((ncol * 2) ^ ((krow & 7) << 4)));
        *(unsigned short*)(kf + base) = f16b(acc[f][r] + bb);
      }
    } else {  // V swizzled image fp16
      char* vf = ws + OFF_V;
      unsigned short h[4];
#pragma unroll
      for (int r = 0; r < 4; r++) h[r] = f16b(acc[f][r] + bb);
      const int mg = mgbase;
      const int bidx = mg >> 12, sg = mg & 4095;
      const int kt = sg >> 5, kin = sg & 31;
      const int e = ncol;
      const size_t img = (size_t)((e >> 1) * 128 +
                         (((e & 1) * 64 + kin * 2) ^ (((e >> 1) & 7) << 4)));
      *(uint2*)(vf + ((size_t)(bidx * 128 + kt)) * 16384 + img) =
          make_uint2((unsigned)h[0] | ((unsigned)h[1] << 16),
                     (unsigned)h[2] | ((unsigned)h[3] << 16));
    }
  }
}

// ---------------- flash attention (fp16 pipeline, kv-split) ----------------
// grid (64 qt, B, 3), block 256 (4 waves; wave w owns q-rows w*16..+15,
// full e=256). KBLK=32, single-buffered K/V via global_load_lds.
// LDS = 36 KB (40 KB at 8KB granule) -> 3 blocks/CU co-resident with nz=3.
// NOTE: keep min-waves at 2 — r5's (256,3) capped VGPR to 84 and spilled.
__global__ __launch_bounds__(256, 2) void k_attn(
    char* __restrict__ ws, float* __restrict__ out, int nz) {
  __shared__ __align__(16) char sbuf[36864];  // 0:K 16K:V 32K:P(4x1K)
  const int t = threadIdx.x, lane = t & 63, w = t >> 6;
  const int qt = blockIdx.x, b = blockIdx.y, z = blockIdx.z;
  const int q0 = qt * 64;
  const int ktq = 128 / nz, ktr = 128 % nz;
  const int kt0 = z * ktq + (z < ktr ? z : ktr);
  const int cnt = ktq + (z < ktr ? 1 : 0);

  // ---- Q fragments (fp16) ----
  f16x8 qf[8];
  {
    const int qrow = q0 + w * 16 + (lane & 15);
    const unsigned short* qp =
        (const unsigned short*)(ws + OFF_Q) + (size_t)(b * Ss + qrow) * Cc;
#pragma unroll
    for (int c = 0; c < 8; c++)
      qf[c] = *(const f16x8*)(qp + c * 32 + (lane >> 4) * 8);
  }

  // ---- staging source offsets (linear: global layout == LDS image) ----
  unsigned srcoff[8];
#pragma unroll
  for (int j = 0; j < 8; j++) {
    const int L = w * 8192 + j * 1024;
    const unsigned rb = (L < 16384) ? (unsigned)OFF_K : (unsigned)OFF_V;
    srcoff[j] = rb + (unsigned)b * 2097152u + (unsigned)kt0 * 16384u +
                (unsigned)(L & 16383) + (unsigned)(lane * 16);
  }

  f32x4 acc[16];
#pragma unroll
  for (int eg = 0; eg < 16; eg++) acc[eg] = (f32x4){0.f, 0.f, 0.f, 0.f};
  float mrun[4] = {-1e30f, -1e30f, -1e30f, -1e30f};
  float lrun[4] = {0.f, 0.f, 0.f, 0.f};

  // ---- prologue: stage tile 0 ----
#pragma unroll
  for (int j = 0; j < 8; j++) gl16(ws + srcoff[j], sbuf + w * 8192 + j * 1024);
  __syncthreads();

  char* const phb = sbuf + 32768 + w * 1024;

  for (int it = 0; it < cnt; it++) {
    // ---- S = Q K^T (fp16 single term) ----
    f32x4 sacc[2];
    sacc[0] = (f32x4){0.f, 0.f, 0.f, 0.f};
    sacc[1] = (f32x4){0.f, 0.f, 0.f, 0.f};
    __builtin_amdgcn_s_setprio(1);
#pragma unroll
    for (int c = 0; c < 8; c++) {
#pragma unroll
      for (int f = 0; f < 2; f++) {
        const int krow = f * 16 + (lane & 15);
        const int kby = krow * 512 + ((c * 64 + (lane >> 4) * 16) ^ ((krow & 7) << 4));
        sacc[f] = mfma16f(qf[c], *(const f16x8*)(sbuf + kby), sacc[f]);
      }
    }
    __builtin_amdgcn_s_setprio(0);

    // ---- online softmax with defer-max (rows q = (lane>>4)*4+r) ----
    float tm[4];
#pragma unroll
    for (int r = 0; r < 4; r++) tm[r] = fmaxf(sacc[0][r], sacc[1][r]);
#pragma unroll
    for (int r = 0; r < 4; r++) {
      tm[r] = fmaxf(tm[r], __shfl_xor(tm[r], 1, 64));
      tm[r] = fmaxf(tm[r], __shfl_xor(tm[r], 2, 64));
      tm[r] = fmaxf(tm[r], __shfl_xor(tm[r], 4, 64));
      tm[r] = fmaxf(tm[r], __shfl_xor(tm[r], 8, 64));
    }
    int ok = 1;
#pragma unroll
    for (int r = 0; r < 4; r++) ok &= (tm[r] <= mrun[r] + 5.5f) ? 1 : 0;
    if (!__all(ok)) {
      float sc[4];
#pragma unroll
      for (int r = 0; r < 4; r++) {
        float mn = fmaxf(mrun[r], tm[r]);
        sc[r] = __expf(mrun[r] - mn);
        mrun[r] = mn;
        lrun[r] *= sc[r];
      }
#pragma unroll
      for (int eg = 0; eg < 16; eg++) {
        acc[eg][0] *= sc[0]; acc[eg][1] *= sc[1];
        acc[eg][2] *= sc[2]; acc[eg][3] *= sc[3];
      }
    }
    float rsum[4] = {0.f, 0.f, 0.f, 0.f};
#pragma unroll
    for (int f = 0; f < 2; f++) {
#pragma unroll
      for (int r = 0; r < 4; r++) {
        float p = __expf(sacc[f][r] - mrun[r]);
        sacc[f][r] = p;
        rsum[r] += p;
      }
    }
#pragma unroll
    for (int r = 0; r < 4; r++) {
      rsum[r] += __shfl_xor(rsum[r], 1, 64);
      rsum[r] += __shfl_xor(rsum[r], 2, 64);
      rsum[r] += __shfl_xor(rsum[r], 4, 64);
      rsum[r] += __shfl_xor(rsum[r], 8, 64);
      lrun[r] += rsum[r];
    }

    // ---- P -> per-wave LDS (fp16, packed-row swizzle) ----
#pragma unroll
    for (int r = 0; r < 4; r++) {
      const unsigned wpk = pkf16(sacc[0][r], sacc[1][r]);
      const int q = (lane >> 4) * 4 + r;
      const int c0 = (lane & 15) * 2;
      const int lineb = (q >> 1) * 128, sw = ((q >> 1) & 7) << 4, half = (q & 1) * 64;
      *(unsigned short*)(phb + lineb + ((half + c0) ^ sw)) = (unsigned short)wpk;
      *(unsigned short*)(phb + lineb + ((half + 32 + c0) ^ sw)) =
          (unsigned short)(wpk >> 16);
    }

    // ---- O += P V (fp16) ----
    {
      const int q = lane & 15;
      const int pby = (q >> 1) * 128 +
                      (((q & 1) * 64 + (lane >> 4) * 16) ^ (((q >> 1) & 7) << 4));
      f16x8 pa = *(const f16x8*)(phb + pby);
      __builtin_amdgcn_s_setprio(1);
#pragma unroll
      for (int eg = 0; eg < 16; eg++) {
        const int erow = eg * 16 + (lane & 15);
        const int vby = (erow >> 1) * 128 +
                        (((erow & 1) * 64 + (lane >> 4) * 16) ^ (((erow >> 1) & 7) << 4));
        acc[eg] = mfma16f(pa, *(const f16x8*)(sbuf + 16384 + vby), acc[eg]);
      }
      __builtin_amdgcn_s_setprio(0);
    }

    __syncthreads();  // all reads of this tile done
    if (it + 1 < cnt) {
#pragma unroll
      for (int j = 0; j < 8; j++) {
        srcoff[j] += 16384;
        gl16(ws + srcoff[j], sbuf + w * 8192 + j * 1024);
      }
    }
    __syncthreads();  // vmcnt(0) drain: next tile resident
  }

  // ---- epilogue: write partial (z0: f32 into out; z>=1: bf16) + m,l ----
  const int qloc0 = w * 16 + (lane >> 4) * 4;
  if (z == 0) {
#pragma unroll
    for (int eg = 0; eg < 16; eg++) {
      const int e = eg * 16 + (lane & 15);
#pragma unroll
      for (int r = 0; r < 4; r++)
        out[((size_t)(b * Ss + q0 + qloc0 + r)) * Ee + e] = acc[eg][r];
    }
  } else {
    unsigned short* p1 = (unsigned short*)(ws + OFF_PML + (size_t)nz * 131072 +
                                           (size_t)(z - 1) * 8388608);
#pragma unroll
    for (int eg = 0; eg < 16; eg++) {
      const int e = eg * 16 + (lane & 15);
#pragma unroll
      for (int r = 0; r < 4; r++)
        p1[((size_t)((b * 64 + qt) * 64 + qloc0 + r)) * 256 + e] =
            (unsigned short)bf_hi(acc[eg][r]);
    }
  }
  if ((lane & 15) == 0) {
    float* pml = (float*)(ws + OFF_PML);
#pragma unroll
    for (int r = 0; r < 4; r++) {
      const int q = qloc0 + r;
      pml[(((size_t)(z * 4 + b) * 64 + qt) * 2 + 0) * 64 + q] = mrun[r];
      pml[(((size_t)(z * 4 + b) * 64 + qt) * 2 + 1) * 64 + q] = lrun[r];
    }
  }
}

// ---------------- combine partials + sigmoid ----------------
// grid (64 qt, B, 4 qz), block 256 (thread = e; 16 q-rows per block).
__global__ __launch_bounds__(256) void k_comb(
    char* __restrict__ ws, float* __restrict__ out, int nz) {
  __shared__ float sm[3][16], sl[3][16];
  const int t = threadIdx.x, qt = blockIdx.x, b = blockIdx.y, qz = blockIdx.z;
  const float* pml = (const float*)(ws + OFF_PML);
  if (t < 16 * nz) {
    const int z = t >> 4, qq = t & 15;
    const int q = qz * 16 + qq;
    sm[z][qq] = pml[(((size_t)(z * 4 + b) * 64 + qt) * 2 + 0) * 64 + q];
    sl[z][qq] = pml[(((size_t)(z * 4 + b) * 64 + qt) * 2 + 1) * 64 + q];
  }
  __syncthreads();
  const unsigned short* p1 =
      (const unsigned short*)(ws + OFF_PML + (size_t)nz * 131072);
  for (int qi = 0; qi < 16; qi++) {
    const int q = qz * 16 + qi;
    const size_t o = ((size_t)(b * Ss + qt * 64 + q)) * Ee + t;
    float M = sm[0][qi];
    for (int z = 1; z < nz; z++) M = fmaxf(M, sm[z][qi]);
    float a0 = __expf(sm[0][qi] - M);
    float num = out[o] * a0, den = sl[0][qi] * a0;
    for (int z = 1; z < nz; z++) {
      float az = __expf(sm[z][qi] - M);
      float oz = bf_f(p1[(size_t)(z - 1) * 4194304 +
                         ((size_t)((b * 64 + qt) * 64 + q)) * 256 + t]);
      num += oz * az;
      den += sl[z][qi] * az;
    }
    float v = num / den;
    out[o] = 1.f / (1.f + __expf(-v));
  }
}

extern "C" void kernel_launch(void* const* d_in, const int* in_sizes, int n_in,
                              void* d_out, int out_size, void* d_ws, size_t ws_size,
                              hipStream_t stream) {
  (void)in_sizes; (void)n_in; (void)out_size; (void)ws_size;
  const float* x  = (const float*)d_in[0];
  const float* Wq = (const float*)d_in[1];
  const float* bq = (const float*)d_in[2];
  const float* Wk = (const float*)d_in[3];
  const float* bk = (const float*)d_in[4];
  const float* Wv = (const float*)d_in[5];
  const float* bv = (const float*)d_in[6];
  float* out = (float*)d_out;
  char* ws = (char*)d_ws;
  float* wt = (float*)ws;  // 768 KB: [3][256][256] W^T

  const int nz = 3;  // 36 KB LDS (40 at 8K granule) -> 3 blocks/CU resident

  hipLaunchKernelGGL(k_transpose, dim3(3), dim3(256), 0, stream, Wq, Wk, Wv, wt);
  hipLaunchKernelGGL(k_proj, dim3(256, 4, 3), dim3(256), 0, stream,
                     x, wt, bq, bk, bv, ws);
  hipLaunchKernelGGL(k_attn, dim3(64, Bb, nz), dim3(256), 0, stream, ws, out, nz);
  hipLaunchKernelGGL(k_comb, dim3(64, Bb, 4), dim3(256), 0, stream, ws, out, nz);
}